// Round 6
// baseline (99.022 us; speedup 1.0000x reference)
//
#include <hip/hip_runtime.h>
#include <cstdint>
#include <cmath>
#include <cstring>

// ============================================================================
// Quanvolution: x (32,3,64,64) f32, params (4,4) f32 -> out (32,4,63,63) f32
//
// Key identity: circuit(patch) = signed sums of |U @ s|^2 where
//   s = kron_w (cos(pi*x_w/2), sin(pi*x_w/2))   (real 16-vector, product state)
//   U = fixed 16x16 unitary from the RandomLayers gate sequence + params.
// K1 builds U (fp64) from the host-replicated gate list; K2 does a 512-FMA
// real-weighted complex matvec per (pixel, channel) + 12->4 maxpool.
//
// Host-side bit-exact replica of np.random.default_rng(0):
//   SeedSequence(0) -> PCG64 (XSL-RR, step-then-output) -> draw stream.
// Draw-path hypothesis matrix (one bench per round):
//   V1 (R1/R4): integers=lemire32(hi-bits), shuffle=lemire32     -> FAILED 1.309
//   V2 (R5/R6, this): integers=lemire32, shuffle=random_interval <- numpy's
//       Generator.shuffle (all paths) draws j = random_interval(bitgen,i):
//       masked LOW bits of next_uint32 with rejection (stream-consistent
//       across array/list shuffles). Lemire is only Generator.integers.
//   Fallback V5: both paths masked (unlikely: 1.17 notes say integers=Lemire).
// R1 fix retained: SeedSequence mix() = x*MIX_MULT_L - y*MIX_MULT_R (sub).
// R5: resubmit V2 unchanged (acquisition timeout — V2 never ran).
// ============================================================================

#define MAXOPS 96

struct OpsArg {
  int n;
  int kind[MAXOPS];   // 0=RX, 1=RY, 2=RZ, 3=CNOT
  int a[MAXOPS];      // rot wire / cnot ctrl
  int b[MAXOPS];      // cnot tgt
  int p[MAXOPS];      // param flat index l*4+i for rot
};

// ---------------------------------------------------------------------------
// Host-side replica of numpy's default_rng(0) stream
// ---------------------------------------------------------------------------
namespace nprng {

struct Pcg64 {
  __uint128_t state, inc;
  bool has_uint32;
  uint32_t uinteger;

  static inline __uint128_t mul() {
    return (((__uint128_t)2549297995355413924ULL) << 64) | 4865540595714422341ULL;
  }
  inline void step() { state = state * mul() + inc; }
  inline uint64_t next64() {                 // pcg64: step FIRST, then output
    step();
    uint64_t hi = (uint64_t)(state >> 64);
    uint64_t lo = (uint64_t)state;
    uint64_t x  = hi ^ lo;
    unsigned r  = (unsigned)(state >> 122) & 63u;   // top 6 bits
    return (x >> r) | (x << ((64u - r) & 63u));     // rotr64
  }
  inline uint32_t next32() {                 // pcg64_next32 half-word buffer
    if (has_uint32) { has_uint32 = false; return uinteger; }
    uint64_t n = next64();
    has_uint32 = true;
    uinteger = (uint32_t)(n >> 32);          // buffer HIGH half
    return (uint32_t)(n & 0xffffffffu);      // return LOW half first
  }
  inline double nextDouble() {               // random_standard_double
    return (double)(next64() >> 11) * (1.0 / 9007199254740992.0);
  }
  // numpy buffered_bounded_lemire_uint32: uniform on [0, rng] inclusive.
  // Used by Generator.integers (use_masked=False path). HIGH bits of v*excl.
  inline uint32_t lemire32(uint32_t rng) {
    const uint32_t rng_excl = rng + 1u;
    uint64_t m = (uint64_t)next32() * (uint64_t)rng_excl;
    uint32_t leftover = (uint32_t)m;
    if (leftover < rng_excl) {
      const uint32_t threshold = (uint32_t)((uint64_t)(0xFFFFFFFFu - rng) % rng_excl);
      while (leftover < threshold) {
        m = (uint64_t)next32() * (uint64_t)rng_excl;
        leftover = (uint32_t)m;
      }
    }
    return (uint32_t)(m >> 32);
  }
  // numpy random_interval (max <= 0xffffffff branch): masked LOW bits with
  // rejection. Used by Generator.shuffle/permutation.  [V2 fix]
  inline uint32_t interval32(uint32_t max) {
    if (max == 0) return 0;
    uint32_t mask = max;
    mask |= mask >> 1; mask |= mask >> 2; mask |= mask >> 4;
    mask |= mask >> 8; mask |= mask >> 16;
    uint32_t value = next32() & mask;
    while (value > max) value = next32() & mask;
    return value;
  }
};

static inline uint32_t hashmix(uint32_t value, uint32_t& hc) {
  value ^= hc;
  hc *= 0x931e8875u;      // MULT_A
  value *= hc;
  value ^= value >> 16;
  return value;
}
static inline uint32_t mixfn(uint32_t x, uint32_t y) {
  // numpy / randutils seed_seq_fe: SUBTRACTION (R1 fix)
  uint32_t r = x * 0xca01f9ddu - y * 0x4973f715u;   // MIX_MULT_L / MIX_MULT_R
  r ^= r >> 16;
  return r;
}

static void make_ops(OpsArg& out) {
  // --- SeedSequence(0), pool_size=4; entropy coerces to uint32 [0] ---
  uint32_t pool[4];
  uint32_t hc = 0x43b0d7e5u;      // INIT_A
  for (int i = 0; i < 4; ++i) pool[i] = hashmix(0u, hc);
  for (int s = 0; s < 4; ++s)
    for (int d = 0; d < 4; ++d)
      if (s != d) pool[d] = mixfn(pool[d], hashmix(pool[s], hc));

  // --- generate_state(4, uint64) -> 8 uint32, little-endian pairs ---
  uint32_t hb = 0x8b51f9ddu;      // INIT_B
  uint32_t w32[8];
  for (int i = 0; i < 8; ++i) {
    uint32_t dv = pool[i & 3];
    dv ^= hb;
    hb *= 0x58f38dedu;            // MULT_B
    dv *= hb;
    dv ^= dv >> 16;
    w32[i] = dv;
  }
  uint64_t val[4];
  for (int i = 0; i < 4; ++i)
    val[i] = (uint64_t)w32[2*i] | ((uint64_t)w32[2*i+1] << 32);

  // --- pcg64_srandom_r(initstate=(val0<<64)|val1, initseq=(val2<<64)|val3) ---
  Pcg64 rng;
  __uint128_t initstate = (((__uint128_t)val[0]) << 64) | val[1];
  __uint128_t initseq   = (((__uint128_t)val[2]) << 64) | val[3];
  rng.state = 0;
  rng.inc = (initseq << 1) | 1;
  rng.step();
  rng.state += initstate;
  rng.step();
  rng.has_uint32 = false;
  rng.uinteger = 0;

  // --- RandomLayers structure sampling (SEED=0, ratio_imprim=0.3) ---
  out.n = 0;
  for (int l = 0; l < 4; ++l) {
    int i = 0;
    while (i < 4) {
      if (rng.nextDouble() > 0.3) {
        int axis = (int)rng.lemire32(2u);  // integers(3): Lemire path
        int wire = (int)rng.lemire32(3u);  // integers(4): Lemire path
        if (out.n < MAXOPS) {
          out.kind[out.n] = axis;          // 0=RX,1=RY,2=RZ
          out.a[out.n] = wire;
          out.b[out.n] = 0;
          out.p[out.n] = l * 4 + i;
          out.n++;
        }
        ++i;
      } else {
        // permutation(4) -> shuffle(arange(4)): Fisher-Yates i=3..1 with
        // j = random_interval(i)  [V2: masked low-bits + rejection]
        int pr[4] = {0, 1, 2, 3};
        for (int k = 3; k >= 1; --k) {
          int j = (int)rng.interval32((uint32_t)k);
          int t = pr[k]; pr[k] = pr[j]; pr[j] = t;
        }
        if (out.n < MAXOPS) {
          out.kind[out.n] = 3;
          out.a[out.n] = pr[0];            // ctrl
          out.b[out.n] = pr[1];            // tgt
          out.p[out.n] = 0;
          out.n++;
        }
      }
    }
  }
}

} // namespace nprng

// ---------------------------------------------------------------------------
// Kernel 1: build U (16x16 complex) in fp64, store fp32 column-major pairs:
//   Uout[(col*16 + k)*2 + {0,1}] = {Re, Im} of U[k][col]
// Thread j evolves column j (state U|j>) through the gate list.
// ---------------------------------------------------------------------------
__global__ __launch_bounds__(64) void build_u_kernel(
    const float* __restrict__ params, float* __restrict__ Uout, OpsArg ops) {
  __shared__ double Lre[16][17], Lim[16][17];
  const int tid = threadIdx.x;
  if (tid >= 16) return;

  for (int k = 0; k < 16; ++k) { Lre[tid][k] = (k == tid) ? 1.0 : 0.0; Lim[tid][k] = 0.0; }

  for (int o = 0; o < ops.n; ++o) {
    const int kind = ops.kind[o];
    if (kind == 3) {                       // CNOT(ctrl=a, tgt=b)
      const int cbit = 8 >> ops.a[o];
      const int tbit = 8 >> ops.b[o];
      for (int k = 0; k < 16; ++k) {
        if ((k & cbit) && !(k & tbit)) {
          const int k1 = k | tbit;
          double tr = Lre[tid][k], ti = Lim[tid][k];
          Lre[tid][k] = Lre[tid][k1]; Lim[tid][k] = Lim[tid][k1];
          Lre[tid][k1] = tr;          Lim[tid][k1] = ti;
        }
      }
    } else {
      const double th = (double)params[ops.p[o]];
      const double c = cos(0.5 * th), s = sin(0.5 * th);
      const int bit = 8 >> ops.a[o];
      for (int k = 0; k < 16; ++k) {
        if (!(k & bit)) {
          const int k1 = k | bit;
          const double r0 = Lre[tid][k],  i0 = Lim[tid][k];
          const double r1 = Lre[tid][k1], i1 = Lim[tid][k1];
          if (kind == 0) {        // RX: [[c,-is],[-is,c]]
            Lre[tid][k]  =  c*r0 + s*i1;  Lim[tid][k]  =  c*i0 - s*r1;
            Lre[tid][k1] =  s*i0 + c*r1;  Lim[tid][k1] = -s*r0 + c*i1;
          } else if (kind == 1) { // RY: [[c,-s],[s,c]]
            Lre[tid][k]  =  c*r0 - s*r1;  Lim[tid][k]  =  c*i0 - s*i1;
            Lre[tid][k1] =  s*r0 + c*r1;  Lim[tid][k1] =  s*i0 + c*i1;
          } else {                // RZ: diag(c-is, c+is)
            Lre[tid][k]  =  c*r0 + s*i0;  Lim[tid][k]  =  c*i0 - s*r0;
            Lre[tid][k1] =  c*r1 - s*i1;  Lim[tid][k1] =  c*i1 + s*r1;
          }
        }
      }
    }
  }

  for (int k = 0; k < 16; ++k) {
    Uout[(tid * 16 + k) * 2 + 0] = (float)Lre[tid][k];
    Uout[(tid * 16 + k) * 2 + 1] = (float)Lim[tid][k];
  }
}

// ---------------------------------------------------------------------------
// Kernel 2: one block per (b, oh); lane ow computes one output pixel.
// ---------------------------------------------------------------------------
__global__ __launch_bounds__(64) void quanv_main_kernel(
    const float* __restrict__ x, const float* __restrict__ U,
    float* __restrict__ out) {
  __shared__ float4 Ulds[128];           // [col*8 + kpair] = (Re,Im,Re,Im)
  __shared__ float2 cs[3][2][64];        // (cos, sin) of pi/2 * x
  const int tid = threadIdx.x;
  const int b  = blockIdx.x / 63;
  const int oh = blockIdx.x % 63;

  #pragma unroll
  for (int i = tid; i < 128; i += 64) Ulds[i] = ((const float4*)U)[i];

  #pragma unroll
  for (int idx = tid; idx < 384; idx += 64) {
    const int c   = idx >> 7;
    const int r   = (idx >> 6) & 1;
    const int col = idx & 63;
    const float v = x[((b * 3 + c) << 12) + ((oh + r) << 6) + col];
    float sn, csn;
    __sincosf(1.57079632679489662f * v, &sn, &csn);
    cs[c][r][col] = make_float2(csn, sn);
  }
  __syncthreads();

  const int ow = tid;
  if (ow >= 63) return;

  // Product-state vectors s^c; flat k = b_w0*8 + b_w1*4 + b_w2*2 + b_w3
  float sv[3][16];
  #pragma unroll
  for (int c = 0; c < 3; ++c) {
    const float2 p00 = cs[c][0][ow], p01 = cs[c][0][ow + 1];
    const float2 p10 = cs[c][1][ow], p11 = cs[c][1][ow + 1];
    const float f01[4] = {p00.x*p01.x, p00.x*p01.y, p00.y*p01.x, p00.y*p01.y};
    const float f23[4] = {p10.x*p11.x, p10.x*p11.y, p10.y*p11.x, p10.y*p11.y};
    #pragma unroll
    for (int a2 = 0; a2 < 4; ++a2)
      #pragma unroll
      for (int b2 = 0; b2 < 4; ++b2)
        sv[c][a2 * 4 + b2] = f01[a2] * f23[b2];
  }

  // t^c = U @ s^c  (complex * real): channels fused over one pass of U
  float tre[3][16], tim[3][16];
  #pragma unroll
  for (int c = 0; c < 3; ++c)
    #pragma unroll
    for (int k = 0; k < 16; ++k) { tre[c][k] = 0.f; tim[c][k] = 0.f; }

  #pragma unroll
  for (int j = 0; j < 16; ++j) {
    #pragma unroll
    for (int kk = 0; kk < 8; ++kk) {
      const float4 u = Ulds[j * 8 + kk];
      #pragma unroll
      for (int c = 0; c < 3; ++c) {
        const float sj = sv[c][j];
        tre[c][2*kk]   = fmaf(u.x, sj, tre[c][2*kk]);
        tim[c][2*kk]   = fmaf(u.y, sj, tim[c][2*kk]);
        tre[c][2*kk+1] = fmaf(u.z, sj, tre[c][2*kk+1]);
        tim[c][2*kk+1] = fmaf(u.w, sj, tim[c][2*kk+1]);
      }
    }
  }

  // <Z_w> per channel, then 12 -> 4 adaptive max pool (flat idx c*4+w, triples)
  float vals[12];
  #pragma unroll
  for (int c = 0; c < 3; ++c) {
    float q[16];
    #pragma unroll
    for (int k = 0; k < 16; ++k)
      q[k] = tre[c][k]*tre[c][k] + tim[c][k]*tim[c][k];
    float tot = 0.f, s8 = 0.f, s4 = 0.f, s2 = 0.f, s1 = 0.f;
    #pragma unroll
    for (int k = 0; k < 16; ++k) {
      tot += q[k];
      if (k & 8) s8 += q[k];
      if (k & 4) s4 += q[k];
      if (k & 2) s2 += q[k];
      if (k & 1) s1 += q[k];
    }
    vals[c*4 + 0] = tot - 2.f * s8;   // wire 0 <-> bit 8 (MSB)
    vals[c*4 + 1] = tot - 2.f * s4;
    vals[c*4 + 2] = tot - 2.f * s2;
    vals[c*4 + 3] = tot - 2.f * s1;
  }

  const int pix = oh * 63 + ow;
  float* ob = out + b * 4 * 3969 + pix;
  ob[0 * 3969] = fmaxf(fmaxf(vals[0], vals[1]),  vals[2]);
  ob[1 * 3969] = fmaxf(fmaxf(vals[3], vals[4]),  vals[5]);
  ob[2 * 3969] = fmaxf(fmaxf(vals[6], vals[7]),  vals[8]);
  ob[3 * 3969] = fmaxf(fmaxf(vals[9], vals[10]), vals[11]);
}

// ---------------------------------------------------------------------------
extern "C" void kernel_launch(void* const* d_in, const int* in_sizes, int n_in,
                              void* d_out, int out_size, void* d_ws, size_t ws_size,
                              hipStream_t stream) {
  (void)in_sizes; (void)n_in; (void)out_size; (void)ws_size;
  const float* x      = (const float*)d_in[0];   // (32,3,64,64)
  const float* params = (const float*)d_in[1];   // (4,4)
  float* out = (float*)d_out;                    // (32,4,63,63)
  float* U   = (float*)d_ws;                     // 512 floats

  OpsArg ops;
  nprng::make_ops(ops);                          // deterministic, host-only

  build_u_kernel<<<1, 64, 0, stream>>>(params, U, ops);
  quanv_main_kernel<<<32 * 63, 64, 0, stream>>>(x, U, out);
}

// Round 14
// 82.598 us; speedup vs baseline: 1.1988x; 1.1988x over previous
//
#include <hip/hip_runtime.h>
#include <cstdint>
#include <cmath>
#include <cstring>

// ============================================================================
// Quanvolution: x (32,3,64,64) f32, params (4,4) f32 -> out (32,4,63,63) f32
//
// circuit(patch) = signed sums of |U @ s|^2,  s = kron_w (cos(pi x_w/2), sin..)
// U = fixed 16x16 unitary from RandomLayers(seed=0) + params.
//
// R6 (passed, 99 us): RNG replica V2 confirmed (shuffle = random_interval
//   masked-rejection; integers = Lemire; SeedSequence mix = subtraction).
//   RNG code below is FROZEN.
// R7 perf: build_u was 56.7 us (serial dependent-LDS fp64 chain, ~120cy/hop).
//   -> rewrite K1: static-index register state via template<BIT,KIND> gates
//      (no LDS, no scratch), parallel fp32 sincos + __shfl param select.
//   -> rewrite K2: channel-sequential (acc 32 regs not 96), no LDS/barrier,
//      U read wave-uniform through L1, __launch_bounds__(64,4) caps VGPR.
//   Two-kernel split kept deliberately: per-dispatch rocprof timings keep the
//   K1 and K2 theories separately attributable in a single bench.
// R8-R14: resubmit R7 unchanged (acquisition timeouts — R7 never ran).
// ============================================================================

#define MAXOPS 96

struct OpsPacked {
  int n;
  int op[MAXOPS];   // kind(2) | a<<2 (2) | b<<4 (2) | p<<6 (4)
};

// ---------------------------------------------------------------------------
// Host-side replica of numpy's default_rng(0) stream  [FROZEN — verified R6]
// ---------------------------------------------------------------------------
namespace nprng {

struct Pcg64 {
  __uint128_t state, inc;
  bool has_uint32;
  uint32_t uinteger;

  static inline __uint128_t mul() {
    return (((__uint128_t)2549297995355413924ULL) << 64) | 4865540595714422341ULL;
  }
  inline void step() { state = state * mul() + inc; }
  inline uint64_t next64() {                 // step FIRST, then output (XSL-RR)
    step();
    uint64_t hi = (uint64_t)(state >> 64);
    uint64_t lo = (uint64_t)state;
    uint64_t x  = hi ^ lo;
    unsigned r  = (unsigned)(state >> 122) & 63u;
    return (x >> r) | (x << ((64u - r) & 63u));
  }
  inline uint32_t next32() {                 // pcg64_next32 half-word buffer
    if (has_uint32) { has_uint32 = false; return uinteger; }
    uint64_t n = next64();
    has_uint32 = true;
    uinteger = (uint32_t)(n >> 32);
    return (uint32_t)(n & 0xffffffffu);
  }
  inline double nextDouble() {
    return (double)(next64() >> 11) * (1.0 / 9007199254740992.0);
  }
  // Generator.integers path: buffered_bounded_lemire_uint32 (HIGH bits)
  inline uint32_t lemire32(uint32_t rng) {
    const uint32_t rng_excl = rng + 1u;
    uint64_t m = (uint64_t)next32() * (uint64_t)rng_excl;
    uint32_t leftover = (uint32_t)m;
    if (leftover < rng_excl) {
      const uint32_t threshold = (uint32_t)((uint64_t)(0xFFFFFFFFu - rng) % rng_excl);
      while (leftover < threshold) {
        m = (uint64_t)next32() * (uint64_t)rng_excl;
        leftover = (uint32_t)m;
      }
    }
    return (uint32_t)(m >> 32);
  }
  // Generator.shuffle path: random_interval (masked LOW bits + rejection)
  inline uint32_t interval32(uint32_t max) {
    if (max == 0) return 0;
    uint32_t mask = max;
    mask |= mask >> 1; mask |= mask >> 2; mask |= mask >> 4;
    mask |= mask >> 8; mask |= mask >> 16;
    uint32_t value = next32() & mask;
    while (value > max) value = next32() & mask;
    return value;
  }
};

static inline uint32_t hashmix(uint32_t value, uint32_t& hc) {
  value ^= hc;
  hc *= 0x931e8875u;
  value *= hc;
  value ^= value >> 16;
  return value;
}
static inline uint32_t mixfn(uint32_t x, uint32_t y) {
  uint32_t r = x * 0xca01f9ddu - y * 0x4973f715u;   // subtraction (R1 fix)
  r ^= r >> 16;
  return r;
}

static void make_ops(OpsPacked& out) {
  uint32_t pool[4];
  uint32_t hc = 0x43b0d7e5u;
  for (int i = 0; i < 4; ++i) pool[i] = hashmix(0u, hc);
  for (int s = 0; s < 4; ++s)
    for (int d = 0; d < 4; ++d)
      if (s != d) pool[d] = mixfn(pool[d], hashmix(pool[s], hc));

  uint32_t hb = 0x8b51f9ddu;
  uint32_t w32[8];
  for (int i = 0; i < 8; ++i) {
    uint32_t dv = pool[i & 3];
    dv ^= hb;
    hb *= 0x58f38dedu;
    dv *= hb;
    dv ^= dv >> 16;
    w32[i] = dv;
  }
  uint64_t val[4];
  for (int i = 0; i < 4; ++i)
    val[i] = (uint64_t)w32[2*i] | ((uint64_t)w32[2*i+1] << 32);

  Pcg64 rng;
  __uint128_t initstate = (((__uint128_t)val[0]) << 64) | val[1];
  __uint128_t initseq   = (((__uint128_t)val[2]) << 64) | val[3];
  rng.state = 0;
  rng.inc = (initseq << 1) | 1;
  rng.step();
  rng.state += initstate;
  rng.step();
  rng.has_uint32 = false;
  rng.uinteger = 0;

  out.n = 0;
  for (int l = 0; l < 4; ++l) {
    int i = 0;
    while (i < 4) {
      if (rng.nextDouble() > 0.3) {
        int axis = (int)rng.lemire32(2u);
        int wire = (int)rng.lemire32(3u);
        if (out.n < MAXOPS)
          out.op[out.n++] = axis | (wire << 2) | ((l * 4 + i) << 6);
        ++i;
      } else {
        int pr[4] = {0, 1, 2, 3};
        for (int k = 3; k >= 1; --k) {
          int j = (int)rng.interval32((uint32_t)k);
          int t = pr[k]; pr[k] = pr[j]; pr[j] = t;
        }
        if (out.n < MAXOPS)
          out.op[out.n++] = 3 | (pr[0] << 2) | (pr[1] << 4);
      }
    }
  }
}

} // namespace nprng

// ---------------------------------------------------------------------------
// K1 gate appliers: ALL register indices compile-time (no LDS, no scratch).
// ---------------------------------------------------------------------------
template <int BIT, int KIND>
__device__ __forceinline__ void apply_rot(float (&re)[16], float (&im)[16],
                                          float c, float s) {
  #pragma unroll
  for (int k = 0; k < 16; ++k) {
    if ((k & BIT) == 0) {
      const int k1 = k | BIT;
      const float r0 = re[k],  i0 = im[k];
      const float r1 = re[k1], i1 = im[k1];
      if (KIND == 0) {        // RX: [[c,-is],[-is,c]]
        re[k]  =  c*r0 + s*i1;  im[k]  =  c*i0 - s*r1;
        re[k1] =  s*i0 + c*r1;  im[k1] = -s*r0 + c*i1;
      } else if (KIND == 1) { // RY: [[c,-s],[s,c]]
        re[k]  =  c*r0 - s*r1;  im[k]  =  c*i0 - s*i1;
        re[k1] =  s*r0 + c*r1;  im[k1] =  s*i0 + c*i1;
      } else {                // RZ: diag(c-is, c+is)
        re[k]  =  c*r0 + s*i0;  im[k]  =  c*i0 - s*r0;
        re[k1] =  c*r1 - s*i1;  im[k1] =  c*i1 + s*r1;
      }
    }
  }
}

template <int CB, int TB>
__device__ __forceinline__ void apply_cnot(float (&re)[16], float (&im)[16]) {
  #pragma unroll
  for (int k = 0; k < 16; ++k) {
    if ((k & CB) != 0 && (k & TB) == 0) {
      const int k1 = k | TB;
      float t;
      t = re[k]; re[k] = re[k1]; re[k1] = t;
      t = im[k]; im[k] = im[k1]; im[k1] = t;
    }
  }
}

// ---------------------------------------------------------------------------
// Kernel 1: build U (16x16 complex fp32). Thread j evolves column j = U|j>.
// Layout: ((float2*)Uout)[col*16 + k] = (Re, Im) of U[k][col].
// Param (c,s): lane t holds sincos(0.5*params[t]); per-op select via __shfl.
// ---------------------------------------------------------------------------
__global__ __launch_bounds__(64) void build_u_kernel(
    const float* __restrict__ params, float* __restrict__ Uout, OpsPacked ops) {
  const int tid = threadIdx.x;
  if (tid >= 16) return;

  float c_own, s_own;
  __sincosf(0.5f * params[tid], &s_own, &c_own);

  float re[16], im[16];
  #pragma unroll
  for (int k = 0; k < 16; ++k) { re[k] = (k == tid) ? 1.f : 0.f; im[k] = 0.f; }

  const int n = ops.n;
  for (int o = 0; o < n; ++o) {
    const int w    = ops.op[o];
    const int kind = w & 3;
    const int a    = (w >> 2) & 3;
    if (kind == 3) {
      const int bsel = (w >> 4) & 3;
      switch (a * 4 + bsel) {              // ctrl bit = 8>>a, tgt bit = 8>>b
        case 1:  apply_cnot<8,4>(re, im); break;
        case 2:  apply_cnot<8,2>(re, im); break;
        case 3:  apply_cnot<8,1>(re, im); break;
        case 4:  apply_cnot<4,8>(re, im); break;
        case 6:  apply_cnot<4,2>(re, im); break;
        case 7:  apply_cnot<4,1>(re, im); break;
        case 8:  apply_cnot<2,8>(re, im); break;
        case 9:  apply_cnot<2,4>(re, im); break;
        case 11: apply_cnot<2,1>(re, im); break;
        case 12: apply_cnot<1,8>(re, im); break;
        case 13: apply_cnot<1,4>(re, im); break;
        case 14: apply_cnot<1,2>(re, im); break;
        default: break;
      }
    } else {
      const int p   = (w >> 6) & 15;
      const float c = __shfl(c_own, p);    // wave-uniform p -> readlane
      const float s = __shfl(s_own, p);
      switch (kind * 4 + a) {              // wire bit = 8>>a
        case 0:  apply_rot<8,0>(re, im, c, s); break;
        case 1:  apply_rot<4,0>(re, im, c, s); break;
        case 2:  apply_rot<2,0>(re, im, c, s); break;
        case 3:  apply_rot<1,0>(re, im, c, s); break;
        case 4:  apply_rot<8,1>(re, im, c, s); break;
        case 5:  apply_rot<4,1>(re, im, c, s); break;
        case 6:  apply_rot<2,1>(re, im, c, s); break;
        case 7:  apply_rot<1,1>(re, im, c, s); break;
        case 8:  apply_rot<8,2>(re, im, c, s); break;
        case 9:  apply_rot<4,2>(re, im, c, s); break;
        case 10: apply_rot<2,2>(re, im, c, s); break;
        case 11: apply_rot<1,2>(re, im, c, s); break;
        default: break;
      }
    }
  }

  float2* U2 = (float2*)Uout;
  #pragma unroll
  for (int k = 0; k < 16; ++k)
    U2[tid * 16 + k] = make_float2(re[k], im[k]);
}

// ---------------------------------------------------------------------------
// Kernel 2: one block (1 wave) per (b, oh); lane ow = one output pixel.
// Channel-sequential to keep ~80 live VGPRs; U read wave-uniform (L1
// broadcast, no LDS, no barrier). launch_bounds(64,4) caps VGPR at 128 so
// the unrolled c-loop cannot CSE-hoist all 512 U floats.
// ---------------------------------------------------------------------------
__global__ __launch_bounds__(64, 4) void quanv_main_kernel(
    const float* __restrict__ x, const float* __restrict__ U,
    float* __restrict__ out) {
  const int tid = threadIdx.x;
  const int b  = blockIdx.x / 63;
  const int oh = blockIdx.x % 63;
  const int ow = tid;
  if (ow >= 63) return;

  const float*  xb = x + ((b * 3) << 12) + (oh << 6) + ow;
  const float4* U4 = (const float4*)U;   // [col*8+kk] = (Re2k,Im2k,Re2k+1,Im2k+1)

  float vals[12];

  #pragma unroll
  for (int c = 0; c < 3; ++c) {
    const float x00 = xb[c * 4096];
    const float x01 = xb[c * 4096 + 1];
    const float x10 = xb[c * 4096 + 64];
    const float x11 = xb[c * 4096 + 65];
    float s00, c00, s01, c01, s10, c10, s11, c11;
    __sincosf(1.57079632679489662f * x00, &s00, &c00);
    __sincosf(1.57079632679489662f * x01, &s01, &c01);
    __sincosf(1.57079632679489662f * x10, &s10, &c10);
    __sincosf(1.57079632679489662f * x11, &s11, &c11);

    const float f01[4] = {c00*c01, c00*s01, s00*c01, s00*s01};
    const float f23[4] = {c10*c11, c10*s11, s10*c11, s10*s11};
    float sv[16];
    #pragma unroll
    for (int a2 = 0; a2 < 4; ++a2)
      #pragma unroll
      for (int b2 = 0; b2 < 4; ++b2)
        sv[a2 * 4 + b2] = f01[a2] * f23[b2];

    float tre[16], tim[16];
    #pragma unroll
    for (int k = 0; k < 16; ++k) { tre[k] = 0.f; tim[k] = 0.f; }

    #pragma unroll
    for (int j = 0; j < 16; ++j) {
      const float sj = sv[j];
      #pragma unroll
      for (int kk = 0; kk < 8; ++kk) {
        const float4 u = U4[j * 8 + kk];
        tre[2*kk]   = fmaf(u.x, sj, tre[2*kk]);
        tim[2*kk]   = fmaf(u.y, sj, tim[2*kk]);
        tre[2*kk+1] = fmaf(u.z, sj, tre[2*kk+1]);
        tim[2*kk+1] = fmaf(u.w, sj, tim[2*kk+1]);
      }
    }

    float tot = 0.f, s8 = 0.f, s4 = 0.f, s2 = 0.f, s1 = 0.f;
    #pragma unroll
    for (int k = 0; k < 16; ++k) {
      const float q = tre[k]*tre[k] + tim[k]*tim[k];
      tot += q;
      if (k & 8) s8 += q;
      if (k & 4) s4 += q;
      if (k & 2) s2 += q;
      if (k & 1) s1 += q;
    }
    vals[c*4 + 0] = tot - 2.f * s8;   // wire 0 <-> bit 8 (MSB)
    vals[c*4 + 1] = tot - 2.f * s4;
    vals[c*4 + 2] = tot - 2.f * s2;
    vals[c*4 + 3] = tot - 2.f * s1;
  }

  const int pix = oh * 63 + ow;
  float* ob = out + b * 4 * 3969 + pix;
  ob[0 * 3969] = fmaxf(fmaxf(vals[0], vals[1]),  vals[2]);
  ob[1 * 3969] = fmaxf(fmaxf(vals[3], vals[4]),  vals[5]);
  ob[2 * 3969] = fmaxf(fmaxf(vals[6], vals[7]),  vals[8]);
  ob[3 * 3969] = fmaxf(fmaxf(vals[9], vals[10]), vals[11]);
}

// ---------------------------------------------------------------------------
extern "C" void kernel_launch(void* const* d_in, const int* in_sizes, int n_in,
                              void* d_out, int out_size, void* d_ws, size_t ws_size,
                              hipStream_t stream) {
  (void)in_sizes; (void)n_in; (void)out_size; (void)ws_size;
  const float* x      = (const float*)d_in[0];   // (32,3,64,64)
  const float* params = (const float*)d_in[1];   // (4,4)
  float* out = (float*)d_out;                    // (32,4,63,63)
  float* U   = (float*)d_ws;                     // 512 floats

  OpsPacked ops;
  nprng::make_ops(ops);                          // deterministic, host-only

  build_u_kernel<<<1, 64, 0, stream>>>(params, U, ops);
  quanv_main_kernel<<<32 * 63, 64, 0, stream>>>(x, U, out);
}

// Round 17
// 76.690 us; speedup vs baseline: 1.2912x; 1.0770x over previous
//
#include <hip/hip_runtime.h>
#include <cstdint>
#include <cmath>
#include <cstring>
#include <utility>

// ============================================================================
// Quanvolution: x (32,3,64,64) f32, params (4,4) f32 -> out (32,4,63,63) f32
//
// circuit(patch) = signed sums of |U @ s|^2,  s = kron_w (cos(pi x_w/2), sin..)
// U = fixed 16x16 unitary from RandomLayers(seed=0) + params.
//
// R6 (passed, 99 us): RNG replica V2 confirmed. RNG logic FROZEN.
// R7/R14 (passed, 82.6 us): K1 switch-loop rewrite only got build_u 56.7->~40us
//   (inferred: dDur=-16.4 ~= dK1; K2 ~2-4us). Instruction accounting can't
//   explain 40us; suspects = scratch spill of re[]/im[] across the 24-way
//   switch join, or I$ thrash from data-dependent jumps into 24 case bodies.
// R15: ops list is a pure function of SEED=0 -> evaluate the FROZEN RNG in
//   constexpr and emit the gate sequence as STRAIGHT-LINE code (template fold,
//   if constexpr per op). No kernarg ops, no switch, no branches; __shfl gets
//   constant lane idx. K2 byte-identical to R7 for attribution.
//   Harness floor note: top-5 dispatches are 256MiB d_ws 0xAA poison fills
//   (~41us @ 81% HBM peak) — harness-owned, not controllable by the kernel.
// R16/R17: resubmit R15 unchanged (acquisition timeouts — R15 never ran).
// ============================================================================

#define MAXOPS 96

struct OpsPacked {
  int n;
  int op[MAXOPS];   // kind(2) | a<<2 (2) | b<<4 (2) | p<<6 (4)
};

// ---------------------------------------------------------------------------
// numpy default_rng(0) replica [FROZEN logic, verified R6] — now constexpr:
// the whole sampling runs at COMPILE TIME; no runtime RNG anywhere.
// ---------------------------------------------------------------------------
namespace nprng {

struct Pcg64 {
  __uint128_t state, inc;
  bool has_uint32;
  uint32_t uinteger;

  static constexpr __uint128_t mul() {
    return (((__uint128_t)2549297995355413924ULL) << 64) | 4865540595714422341ULL;
  }
  constexpr void step() { state = state * mul() + inc; }
  constexpr uint64_t next64() {               // step FIRST, then output (XSL-RR)
    step();
    uint64_t hi = (uint64_t)(state >> 64);
    uint64_t lo = (uint64_t)state;
    uint64_t x  = hi ^ lo;
    unsigned r  = (unsigned)(state >> 122) & 63u;
    return (x >> r) | (x << ((64u - r) & 63u));
  }
  constexpr uint32_t next32() {               // pcg64_next32 half-word buffer
    if (has_uint32) { has_uint32 = false; return uinteger; }
    uint64_t n = next64();
    has_uint32 = true;
    uinteger = (uint32_t)(n >> 32);
    return (uint32_t)(n & 0xffffffffu);
  }
  constexpr double nextDouble() {
    return (double)(next64() >> 11) * (1.0 / 9007199254740992.0);
  }
  // Generator.integers path: buffered_bounded_lemire_uint32 (HIGH bits)
  constexpr uint32_t lemire32(uint32_t rng) {
    const uint32_t rng_excl = rng + 1u;
    uint64_t m = (uint64_t)next32() * (uint64_t)rng_excl;
    uint32_t leftover = (uint32_t)m;
    if (leftover < rng_excl) {
      const uint32_t threshold = (uint32_t)((uint64_t)(0xFFFFFFFFu - rng) % rng_excl);
      while (leftover < threshold) {
        m = (uint64_t)next32() * (uint64_t)rng_excl;
        leftover = (uint32_t)m;
      }
    }
    return (uint32_t)(m >> 32);
  }
  // Generator.shuffle path: random_interval (masked LOW bits + rejection)
  constexpr uint32_t interval32(uint32_t max) {
    if (max == 0) return 0;
    uint32_t mask = max;
    mask |= mask >> 1; mask |= mask >> 2; mask |= mask >> 4;
    mask |= mask >> 8; mask |= mask >> 16;
    uint32_t value = next32() & mask;
    while (value > max) value = next32() & mask;
    return value;
  }
};

constexpr uint32_t hashmix(uint32_t value, uint32_t& hc) {
  value ^= hc;
  hc *= 0x931e8875u;
  value *= hc;
  value ^= value >> 16;
  return value;
}
constexpr uint32_t mixfn(uint32_t x, uint32_t y) {
  uint32_t r = x * 0xca01f9ddu - y * 0x4973f715u;   // subtraction (R1 fix)
  r ^= r >> 16;
  return r;
}

constexpr OpsPacked make_ops() {
  OpsPacked out{};
  uint32_t pool[4] = {0, 0, 0, 0};
  uint32_t hc = 0x43b0d7e5u;
  for (int i = 0; i < 4; ++i) pool[i] = hashmix(0u, hc);
  for (int s = 0; s < 4; ++s)
    for (int d = 0; d < 4; ++d)
      if (s != d) pool[d] = mixfn(pool[d], hashmix(pool[s], hc));

  uint32_t hb = 0x8b51f9ddu;
  uint32_t w32[8] = {};
  for (int i = 0; i < 8; ++i) {
    uint32_t dv = pool[i & 3];
    dv ^= hb;
    hb *= 0x58f38dedu;
    dv *= hb;
    dv ^= dv >> 16;
    w32[i] = dv;
  }
  uint64_t val[4] = {};
  for (int i = 0; i < 4; ++i)
    val[i] = (uint64_t)w32[2*i] | ((uint64_t)w32[2*i+1] << 32);

  Pcg64 rng{};
  __uint128_t initstate = (((__uint128_t)val[0]) << 64) | val[1];
  __uint128_t initseq   = (((__uint128_t)val[2]) << 64) | val[3];
  rng.state = 0;
  rng.inc = (initseq << 1) | 1;
  rng.step();
  rng.state += initstate;
  rng.step();
  rng.has_uint32 = false;
  rng.uinteger = 0;

  out.n = 0;
  for (int l = 0; l < 4; ++l) {
    int i = 0;
    while (i < 4) {
      if (rng.nextDouble() > 0.3) {
        int axis = (int)rng.lemire32(2u);
        int wire = (int)rng.lemire32(3u);
        if (out.n < MAXOPS)
          out.op[out.n++] = axis | (wire << 2) | ((l * 4 + i) << 6);
        ++i;
      } else {
        int pr[4] = {0, 1, 2, 3};
        for (int k = 3; k >= 1; --k) {
          int j = (int)rng.interval32((uint32_t)k);
          int t = pr[k]; pr[k] = pr[j]; pr[j] = t;
        }
        if (out.n < MAXOPS)
          out.op[out.n++] = 3 | (pr[0] << 2) | (pr[1] << 4);
      }
    }
  }
  return out;
}

} // namespace nprng

constexpr OpsPacked OPS = nprng::make_ops();
static_assert(OPS.n > 0 && OPS.n <= MAXOPS, "ops sampling sanity");

// ---------------------------------------------------------------------------
// Gate appliers: compile-time bit masks, static register indices.
// ---------------------------------------------------------------------------
template <int BIT, int KIND>
__device__ __forceinline__ void apply_rot(float (&re)[16], float (&im)[16],
                                          float c, float s) {
  #pragma unroll
  for (int k = 0; k < 16; ++k) {
    if ((k & BIT) == 0) {
      const int k1 = k | BIT;
      const float r0 = re[k],  i0 = im[k];
      const float r1 = re[k1], i1 = im[k1];
      if (KIND == 0) {        // RX: [[c,-is],[-is,c]]
        re[k]  =  c*r0 + s*i1;  im[k]  =  c*i0 - s*r1;
        re[k1] =  s*i0 + c*r1;  im[k1] = -s*r0 + c*i1;
      } else if (KIND == 1) { // RY: [[c,-s],[s,c]]
        re[k]  =  c*r0 - s*r1;  im[k]  =  c*i0 - s*i1;
        re[k1] =  s*r0 + c*r1;  im[k1] =  s*i0 + c*i1;
      } else {                // RZ: diag(c-is, c+is)
        re[k]  =  c*r0 + s*i0;  im[k]  =  c*i0 - s*r0;
        re[k1] =  c*r1 - s*i1;  im[k1] =  c*i1 + s*r1;
      }
    }
  }
}

template <int CB, int TB>
__device__ __forceinline__ void apply_cnot(float (&re)[16], float (&im)[16]) {
  #pragma unroll
  for (int k = 0; k < 16; ++k) {
    if ((k & CB) != 0 && (k & TB) == 0) {
      const int k1 = k | TB;
      float t;
      t = re[k]; re[k] = re[k1]; re[k1] = t;
      t = im[k]; im[k] = im[k1]; im[k1] = t;
    }
  }
}

// Straight-line op emission: one inlined, branch-free body per compile-time op.
template <int O>
__device__ __forceinline__ void apply_one(float (&re)[16], float (&im)[16],
                                          float c_own, float s_own) {
  if constexpr (O < OPS.n) {
    constexpr int w    = OPS.op[O];
    constexpr int kind = w & 3;
    constexpr int a    = (w >> 2) & 3;
    if constexpr (kind == 3) {
      constexpr int b = (w >> 4) & 3;
      apply_cnot<(8 >> a), (8 >> b)>(re, im);
    } else {
      constexpr int p = (w >> 6) & 15;
      const float c = __shfl(c_own, p);   // constant lane idx -> readlane
      const float s = __shfl(s_own, p);
      apply_rot<(8 >> a), kind>(re, im, c, s);
    }
  }
}

template <int... Os>
__device__ __forceinline__ void apply_seq(std::integer_sequence<int, Os...>,
                                          float (&re)[16], float (&im)[16],
                                          float c_own, float s_own) {
  (apply_one<Os>(re, im, c_own, s_own), ...);   // left-to-right sequenced
}

// ---------------------------------------------------------------------------
// Kernel 1: build U (16x16 complex fp32). Thread j evolves column j = U|j>.
// Layout: ((float2*)Uout)[col*16 + k] = (Re, Im) of U[k][col].
// Gate sequence is compile-time: zero branches, zero op fetches.
// ---------------------------------------------------------------------------
__global__ __launch_bounds__(64) void build_u_kernel(
    const float* __restrict__ params, float* __restrict__ Uout) {
  const int tid = threadIdx.x;
  if (tid >= 16) return;

  float c_own, s_own;
  __sincosf(0.5f * params[tid], &s_own, &c_own);

  float re[16], im[16];
  #pragma unroll
  for (int k = 0; k < 16; ++k) { re[k] = (k == tid) ? 1.f : 0.f; im[k] = 0.f; }

  apply_seq(std::make_integer_sequence<int, MAXOPS>{}, re, im, c_own, s_own);

  float2* U2 = (float2*)Uout;
  #pragma unroll
  for (int k = 0; k < 16; ++k)
    U2[tid * 16 + k] = make_float2(re[k], im[k]);
}

// ---------------------------------------------------------------------------
// Kernel 2: one block (1 wave) per (b, oh); lane ow = one output pixel.
// BYTE-IDENTICAL to R7/R14 (keeps K1-vs-K2 attribution clean this round).
// ---------------------------------------------------------------------------
__global__ __launch_bounds__(64, 4) void quanv_main_kernel(
    const float* __restrict__ x, const float* __restrict__ U,
    float* __restrict__ out) {
  const int tid = threadIdx.x;
  const int b  = blockIdx.x / 63;
  const int oh = blockIdx.x % 63;
  const int ow = tid;
  if (ow >= 63) return;

  const float*  xb = x + ((b * 3) << 12) + (oh << 6) + ow;
  const float4* U4 = (const float4*)U;   // [col*8+kk] = (Re2k,Im2k,Re2k+1,Im2k+1)

  float vals[12];

  #pragma unroll
  for (int c = 0; c < 3; ++c) {
    const float x00 = xb[c * 4096];
    const float x01 = xb[c * 4096 + 1];
    const float x10 = xb[c * 4096 + 64];
    const float x11 = xb[c * 4096 + 65];
    float s00, c00, s01, c01, s10, c10, s11, c11;
    __sincosf(1.57079632679489662f * x00, &s00, &c00);
    __sincosf(1.57079632679489662f * x01, &s01, &c01);
    __sincosf(1.57079632679489662f * x10, &s10, &c10);
    __sincosf(1.57079632679489662f * x11, &s11, &c11);

    const float f01[4] = {c00*c01, c00*s01, s00*c01, s00*s01};
    const float f23[4] = {c10*c11, c10*s11, s10*c11, s10*s11};
    float sv[16];
    #pragma unroll
    for (int a2 = 0; a2 < 4; ++a2)
      #pragma unroll
      for (int b2 = 0; b2 < 4; ++b2)
        sv[a2 * 4 + b2] = f01[a2] * f23[b2];

    float tre[16], tim[16];
    #pragma unroll
    for (int k = 0; k < 16; ++k) { tre[k] = 0.f; tim[k] = 0.f; }

    #pragma unroll
    for (int j = 0; j < 16; ++j) {
      const float sj = sv[j];
      #pragma unroll
      for (int kk = 0; kk < 8; ++kk) {
        const float4 u = U4[j * 8 + kk];
        tre[2*kk]   = fmaf(u.x, sj, tre[2*kk]);
        tim[2*kk]   = fmaf(u.y, sj, tim[2*kk]);
        tre[2*kk+1] = fmaf(u.z, sj, tre[2*kk+1]);
        tim[2*kk+1] = fmaf(u.w, sj, tim[2*kk+1]);
      }
    }

    float tot = 0.f, s8 = 0.f, s4 = 0.f, s2 = 0.f, s1 = 0.f;
    #pragma unroll
    for (int k = 0; k < 16; ++k) {
      const float q = tre[k]*tre[k] + tim[k]*tim[k];
      tot += q;
      if (k & 8) s8 += q;
      if (k & 4) s4 += q;
      if (k & 2) s2 += q;
      if (k & 1) s1 += q;
    }
    vals[c*4 + 0] = tot - 2.f * s8;   // wire 0 <-> bit 8 (MSB)
    vals[c*4 + 1] = tot - 2.f * s4;
    vals[c*4 + 2] = tot - 2.f * s2;
    vals[c*4 + 3] = tot - 2.f * s1;
  }

  const int pix = oh * 63 + ow;
  float* ob = out + b * 4 * 3969 + pix;
  ob[0 * 3969] = fmaxf(fmaxf(vals[0], vals[1]),  vals[2]);
  ob[1 * 3969] = fmaxf(fmaxf(vals[3], vals[4]),  vals[5]);
  ob[2 * 3969] = fmaxf(fmaxf(vals[6], vals[7]),  vals[8]);
  ob[3 * 3969] = fmaxf(fmaxf(vals[9], vals[10]), vals[11]);
}

// ---------------------------------------------------------------------------
extern "C" void kernel_launch(void* const* d_in, const int* in_sizes, int n_in,
                              void* d_out, int out_size, void* d_ws, size_t ws_size,
                              hipStream_t stream) {
  (void)in_sizes; (void)n_in; (void)out_size; (void)ws_size;
  const float* x      = (const float*)d_in[0];   // (32,3,64,64)
  const float* params = (const float*)d_in[1];   // (4,4)
  float* out = (float*)d_out;                    // (32,4,63,63)
  float* U   = (float*)d_ws;                     // 512 floats

  build_u_kernel<<<1, 64, 0, stream>>>(params, U);
  quanv_main_kernel<<<32 * 63, 64, 0, stream>>>(x, U, out);
}